// Round 10
// baseline (647.929 us; speedup 1.0000x reference)
//
#include <hip/hip_runtime.h>
#include <hip/hip_bf16.h>
#include <cstdint>
#include <cstddef>
#include <cmath>

#define N_TOK 4096
#define EMB   2048
#define DATT  2048

typedef __attribute__((ext_vector_type(8))) short short8;
typedef __attribute__((ext_vector_type(4))) short shortx4;
typedef __attribute__((ext_vector_type(4))) float f32x4;

#define MFMA(a, b, c) __builtin_amdgcn_mfma_f32_16x16x32_bf16(a, b, c, 0, 0, 0)

__device__ __forceinline__ short f2bs(float f) {
  __hip_bfloat16 h = __float2bfloat16(f);   // RNE
  return __builtin_bit_cast(short, h);
}
__device__ __forceinline__ float bs2f(short s) {
  return __uint_as_float(((unsigned)(unsigned short)s) << 16);
}
__device__ __forceinline__ float ldin(const void* p, size_t i, int isbf) {
  if (isbf) {
    unsigned short u = ((const unsigned short*)p)[i];
    return __uint_as_float(((unsigned int)u) << 16);
  }
  return ((const float*)p)[i];
}

// Fragment-major swizzle: element (r, c) of an (R x K) operand lives at
//   ((r>>7)*(K/8) + (c>>3))*1024 + (r&127)*8 + (c&7)
__device__ __forceinline__ size_t swz(int r, int c, int kdim) {
  return ((size_t)((r >> 7) * (kdim >> 3) + (c >> 3)) << 10) +
         (size_t)((r & 127) << 3) + (c & 7);
}

// async global->LDS, 16B per lane; lds dest must be wave-uniform base
__device__ __forceinline__ void gl16(const short* g, short* l) {
  __builtin_amdgcn_global_load_lds(
      (const __attribute__((address_space(1))) unsigned int*)(const void*)g,
      (__attribute__((address_space(3))) unsigned int*)(void*)l, 16, 0, 0);
}

// ======================================================================
// 128x128-tile, 4-wave, 2-buffer GEMM core (proven: score3 @122us, 37% Mfma).
// stage(t+1) issued AFTER the barrier of tile t; one barrier per tile.
// ======================================================================
template <bool THREE>
__device__ __forceinline__ void gemm_core(const short* Ah, const short* Al,
                                          const short* Bh, const short* Bl,
                                          int chunks, int apan, int bpan,
                                          int kmax, short* lds,
                                          f32x4 acc[4][4]) {
  const int NSL = THREE ? 4 : 2;
  int tid = threadIdx.x;
  int lane = tid & 63;
  int wave = tid >> 6;
  int ln = lane & 15, quad = lane >> 4;
  int wm = (wave >> 1) * 64, wn = (wave & 1) * 64;
  int wofs = wave * 512;

  auto stage = [&](int b, int k0) {
    size_t ao = ((size_t)(apan * chunks + (k0 >> 3))) << 10;
    size_t bo = ((size_t)(bpan * chunks + (k0 >> 3))) << 10;
    short* base = lds + b * NSL * 4096;
    const short* sa = Ah + ao + tid * 8;
    const short* sb = Bh + bo + tid * 8;
    gl16(sa,        base + wofs);
    gl16(sa + 2048, base + wofs + 2048);
    gl16(sb,        base + 4096 + wofs);
    gl16(sb + 2048, base + 4096 + wofs + 2048);
    if (THREE) {
      const short* sal = Al + ao + tid * 8;
      const short* sbl = Bl + bo + tid * 8;
      gl16(sal,        base + 8192 + wofs);
      gl16(sal + 2048, base + 8192 + wofs + 2048);
      gl16(sbl,        base + 12288 + wofs);
      gl16(sbl + 2048, base + 12288 + wofs + 2048);
    }
  };

  stage(0, 0);
  int cur = 0;
  int abase = quad * 1024 + (wm + ln) * 8;
  int bbase = quad * 1024 + (wn + ln) * 8;
  for (int k0 = 0; k0 < kmax; k0 += 32) {
    __syncthreads();
    if (k0 + 32 < kmax) stage(cur ^ 1, k0 + 32);
    const short* B0 = lds + cur * NSL * 4096;
    short8 fah[4], fbh[4];
#pragma unroll
    for (int i = 0; i < 4; ++i) fah[i] = *(const short8*)(B0 + abase + i * 128);
#pragma unroll
    for (int j = 0; j < 4; ++j) fbh[j] = *(const short8*)(B0 + 4096 + bbase + j * 128);
    if (THREE) {
      short8 fal[4], fbl[4];
#pragma unroll
      for (int i = 0; i < 4; ++i) fal[i] = *(const short8*)(B0 + 8192 + abase + i * 128);
#pragma unroll
      for (int j = 0; j < 4; ++j) fbl[j] = *(const short8*)(B0 + 12288 + bbase + j * 128);
#pragma unroll
      for (int j = 0; j < 4; ++j)
#pragma unroll
        for (int i = 0; i < 4; ++i) {
          acc[i][j] = MFMA(fah[i], fbh[j], acc[i][j]);
          acc[i][j] = MFMA(fah[i], fbl[j], acc[i][j]);
          acc[i][j] = MFMA(fal[i], fbh[j], acc[i][j]);
        }
    } else {
#pragma unroll
      for (int j = 0; j < 4; ++j)
#pragma unroll
        for (int i = 0; i < 4; ++i) acc[i][j] = MFMA(fah[i], fbh[j], acc[i][j]);
    }
    cur ^= 1;
  }
}

// ======================================================================
// 3-term depth-2 core: (AP*128) x (BP*128) tile, AP+BP==3, 8 waves (512
// threads), 3 LDS buffers of 48KB (144KB total), ONE barrier per K-tile,
// steady-state s_waitcnt vmcnt(6); stage(t) issued during tile t-2 ->
// TWO tiles of latency cover. Used where grid == 256 (1/CU): k_proj3.
// ======================================================================
template <int AP, int BP>
__device__ __forceinline__ void gemm8(const short* __restrict__ Ah,
                                      const short* __restrict__ Al,
                                      const short* __restrict__ Bh,
                                      const short* __restrict__ Bl,
                                      int chunks, int apan, int bpan,
                                      int kmax, short* lds, f32x4 acc[4][4]) {
  constexpr int ASZ = AP * 4096;
  constexpr int BSZ = BP * 4096;
  constexpr int OAL = ASZ;
  constexpr int OBH = 2 * ASZ;
  constexpr int OBL = 2 * ASZ + BSZ;
  constexpr int BUF = 2 * ASZ + 2 * BSZ;  // 24576 shorts = 48KB
  constexpr int NNW = BP * 2;
  int tid = threadIdx.x;
  int lane = tid & 63, wave = tid >> 6;
  int ln = lane & 15, quad = lane >> 4;
  int wm = (wave / NNW) * 64, wn = (wave % NNW) * 64;
  int nt = kmax >> 5;

  auto sp = [&](int b, int t, int p) {
    short* base = lds + b * BUF;
    const short* g;
    short* l;
    if (p < AP)               { g = Ah + (((size_t)(apan + p) * chunks + (t << 2)) << 10);          l = base + p * 4096; }
    else if (p < 2 * AP)      { int q = p - AP;      g = Al + (((size_t)(apan + q) * chunks + (t << 2)) << 10); l = base + OAL + q * 4096; }
    else if (p < 2 * AP + BP) { int q = p - 2 * AP;  g = Bh + (((size_t)(bpan + q) * chunks + (t << 2)) << 10); l = base + OBH + q * 4096; }
    else                      { int q = p - 2 * AP - BP; g = Bl + (((size_t)(bpan + q) * chunks + (t << 2)) << 10); l = base + OBL + q * 4096; }
    gl16(g + tid * 8, l + wave * 512);
  };

#pragma unroll
  for (int p = 0; p < 6; ++p) sp(0, 0, p);
  if (nt > 1) {
#pragma unroll
    for (int p = 0; p < 6; ++p) sp(1, 1, p);
  }

  int abase = (wm & 128) * 32 + quad * 1024 + ((wm & 64) + ln) * 8;
  int bbase = (wn & 128) * 32 + quad * 1024 + ((wn & 64) + ln) * 8;
  int bi = 0;
  for (int t = 0; t < nt; ++t) {
    if (t + 1 < nt) asm volatile("s_waitcnt vmcnt(6)" ::: "memory");
    else            asm volatile("s_waitcnt vmcnt(0)" ::: "memory");
    __builtin_amdgcn_s_barrier();          // all waves' DMA for buf[bi] landed
    __builtin_amdgcn_sched_barrier(0);     // no LDS read hoists above

    const short* L = lds + bi * BUF;
    int pi = bi + 2; if (pi > 2) pi -= 3;
    bool pf = (t + 2 < nt);

    short8 bh[4], bl[4];
#pragma unroll
    for (int j = 0; j < 4; ++j) {
      bh[j] = *(const short8*)(L + OBH + bbase + j * 128);
      bl[j] = *(const short8*)(L + OBL + bbase + j * 128);
    }
#pragma unroll
    for (int i = 0; i < 4; ++i) {
      short8 ah = *(const short8*)(L + abase + i * 128);
      short8 al = *(const short8*)(L + OAL + abase + i * 128);
      if (pf) {                            // interleave stage issue 2/2/1/1
        if (i == 0)      { sp(pi, t + 2, 0); sp(pi, t + 2, 1); }
        else if (i == 1) { sp(pi, t + 2, 2); sp(pi, t + 2, 3); }
        else if (i == 2) { sp(pi, t + 2, 4); }
        else             { sp(pi, t + 2, 5); }
      }
      __builtin_amdgcn_s_setprio(1);
#pragma unroll
      for (int j = 0; j < 4; ++j) {
        acc[i][j] = MFMA(ah, bh[j], acc[i][j]);
        acc[i][j] = MFMA(ah, bl[j], acc[i][j]);
        acc[i][j] = MFMA(al, bh[j], acc[i][j]);
      }
      __builtin_amdgcn_s_setprio(0);
    }
    ++bi; if (bi > 2) bi = 0;
  }
}

// ======================================================================
// 1-term depth-2 core (proven): 128x128, 4 waves, 3 buffers (48KB),
// one barrier per tile, counted vmcnt(4).
// ======================================================================
__device__ __forceinline__ void gemm1d2(const short* __restrict__ Ah,
                                        const short* __restrict__ Bh,
                                        int chunks, int apan, int bpan,
                                        int kmax, short* lds, f32x4 acc[4][4]) {
  int tid = threadIdx.x;
  int lane = tid & 63, wave = tid >> 6;
  int ln = lane & 15, quad = lane >> 4;
  int wm = (wave >> 1) * 64, wn = (wave & 1) * 64;
  int wofs = wave * 512;
  int nt = kmax >> 5;

  auto stage = [&](int b, int t) {
    size_t ao = ((size_t)(apan * chunks + (t << 2))) << 10;
    size_t bo = ((size_t)(bpan * chunks + (t << 2))) << 10;
    short* base = lds + b * 8192;
    gl16(Ah + ao + tid * 8,        base + wofs);
    gl16(Ah + ao + 2048 + tid * 8, base + wofs + 2048);
    gl16(Bh + bo + tid * 8,        base + 4096 + wofs);
    gl16(Bh + bo + 2048 + tid * 8, base + 4096 + wofs + 2048);
  };
  stage(0, 0);
  if (nt > 1) stage(1, 1);

  int abase = quad * 1024 + (wm + ln) * 8;
  int bbase = quad * 1024 + (wn + ln) * 8;
  int bi = 0;
  for (int t = 0; t < nt; ++t) {
    if (t + 1 < nt) asm volatile("s_waitcnt vmcnt(4)" ::: "memory");
    else            asm volatile("s_waitcnt vmcnt(0)" ::: "memory");
    __builtin_amdgcn_s_barrier();
    __builtin_amdgcn_sched_barrier(0);
    int pi = bi + 2; if (pi > 2) pi -= 3;
    if (t + 2 < nt) stage(pi, t + 2);
    const short* L = lds + bi * 8192;
    short8 fah[4], fbh[4];
#pragma unroll
    for (int i = 0; i < 4; ++i) fah[i] = *(const short8*)(L + abase + i * 128);
#pragma unroll
    for (int j = 0; j < 4; ++j) fbh[j] = *(const short8*)(L + 4096 + bbase + j * 128);
#pragma unroll
    for (int j = 0; j < 4; ++j)
#pragma unroll
      for (int i = 0; i < 4; ++i) acc[i][j] = MFMA(fah[i], fbh[j], acc[i][j]);
    ++bi; if (bi > 2) bi = 0;
  }
}

// ---------- sniff input dtype ----------
__global__ void k_sniff(const void* x, int* flag) {
  if (threadIdx.x == 0 && blockIdx.x == 0) {
    const unsigned short* u = (const unsigned short*)x;
    int bf = 1;
    for (int i = 0; i < 256; ++i) {
      unsigned short v = u[i];
      if ((v & 0x8000u) || ((v & 0x7FFFu) >= 0x3F80u)) { bf = 0; break; }
    }
    *flag = bf;
  }
}

// ---------- xbar[e] = mean of X over first 256 rows ----------
__global__ __launch_bounds__(256) void k_xbar(const void* X, float* xbar,
                                              const int* flagp) {
  int isbf = *flagp;
  int e = blockIdx.x * 256 + threadIdx.x;
  float s = 0.f;
  for (int r = 0; r < 256; ++r) s += ldin(X, (size_t)r * EMB + e, isbf);
  xbar[e] = s * (1.f / 256.f);
}

// ---------- split X -> swizzled Xh, Xl ----------
__global__ __launch_bounds__(256) void k_split_x(const void* X, short* Xh, short* Xl,
                                                 const int* flagp) {
  int isbf = *flagp;
  size_t base = ((size_t)blockIdx.x * 256 + threadIdx.x) * 4;
  int r = (int)(base >> 11), c = (int)(base & 2047);
  shortx4 h, l;
#pragma unroll
  for (int u = 0; u < 4; ++u) {
    float x = ldin(X, base + u, isbf);
    short hh = f2bs(x);
    h[u] = hh;
    l[u] = f2bs(x - bs2f(hh));
  }
  size_t o = swz(r, c, EMB);
  *(shortx4*)(Xh + o) = h;
  *(shortx4*)(Xl + o) = l;
}

// ---------- transpose + split W -> swizzled Wth (+ Wtl) ----------
__global__ __launch_bounds__(256) void k_transpose_split(const void* W, short* Wth,
                                                         short* Wtl, int R, int C,
                                                         const int* flagp, int wlo) {
  __shared__ float T[64][65];
  int isbf = *flagp;
  int r0 = blockIdx.y * 64, c0 = blockIdx.x * 64;
  int tid = threadIdx.x;
#pragma unroll
  for (int it = 0; it < 16; ++it) {
    int idx = tid + it * 256;
    int row = idx >> 6, col = idx & 63;
    T[row][col] = ldin(W, (size_t)(r0 + row) * C + c0 + col, isbf);
  }
  __syncthreads();
#pragma unroll
  for (int it = 0; it < 16; ++it) {
    int idx = tid + it * 256;
    int row = idx >> 6, col = idx & 63;
    float x = T[col][row];
    short h = f2bs(x);
    size_t o = swz(c0 + row, r0 + col, R);
    Wth[o] = h;
    if (wlo) Wtl[o] = f2bs(x - bs2f(h));
  }
}

// ---------- kbar[d] = sum_e xbar[e] * Wk[e][d] ----------
__global__ __launch_bounds__(256) void k_kbar(const short* Wth, const short* Wtl,
                                              const float* xbar, float* kbar) {
  int d = blockIdx.x;
  float s = 0.f;
  for (int e = threadIdx.x; e < EMB; e += 256) {
    size_t o = swz(d, e, EMB);
    s += xbar[e] * (bs2f(Wth[o]) + bs2f(Wtl[o]));
  }
  __shared__ float red[4];
#pragma unroll
  for (int off = 32; off > 0; off >>= 1) s += __shfl_down(s, off);
  if ((threadIdx.x & 63) == 0) red[threadIdx.x >> 6] = s;
  __syncthreads();
  if (threadIdx.x == 0) kbar[d] = red[0] + red[1] + red[2] + red[3];
}

// ---------- 3-term depth-2 projection GEMM: 256x128 tile, 8 waves ----------
__global__ __launch_bounds__(512, 2) void k_proj3(const short* Ah, const short* Al,
                                                  const short* Bh, const short* Bl,
                                                  short* Ch, short* Cl,
                                                  const float* bias) {
  __shared__ short lds[3 * 24576];   // 144 KB, 3-buffer rotation
  int bid = blockIdx.x;
  int s = ((bid & 7) << 5) | (bid >> 3);
  int row0 = (s >> 4) << 8, col0 = (s & 15) << 7;
  f32x4 acc[4][4] = {};
  gemm8<2, 1>(Ah, Al, Bh, Bl, EMB >> 3, row0 >> 7, col0 >> 7, EMB, lds, acc);
  int tid = threadIdx.x;
  int wave = tid >> 6, lane = tid & 63;
  int ln = lane & 15, quad = lane >> 4;
  int wm = (wave >> 1) * 64, wn = (wave & 1) * 64;   // NNW=2
#pragma unroll
  for (int i = 0; i < 4; ++i)
#pragma unroll
    for (int j = 0; j < 4; ++j)
#pragma unroll
      for (int r = 0; r < 4; ++r) {
        int row = row0 + wm + i * 16 + quad * 4 + r;
        int col = col0 + wn + j * 16 + ln;
        float x = acc[i][j][r];
        if (bias) x -= bias[col];
        short h = f2bs(x);
        size_t o = swz(row, col, DATT);
        Ch[o] = h;
        Cl[o] = f2bs(x - bs2f(h));
      }
}

// ---------- 1-term depth-2 V projection: Vt = Wvt @ X^T ----------
__global__ __launch_bounds__(256, 3) void k_proj1(const short* Ah, const short* Bh,
                                                  short* Ch) {
  __shared__ short lds[3 * 8192];   // 48 KB -> 3 blocks/CU
  int bid = blockIdx.x;
  int s = ((bid & 7) << 6) | (bid >> 3);
  int row0 = (s >> 5) << 7, col0 = (s & 31) << 7;   // row=d band, col=token
  f32x4 acc[4][4] = {};
  gemm1d2(Ah, Bh, EMB >> 3, row0 >> 7, col0 >> 7, EMB, lds, acc);
  int tid = threadIdx.x;
  int wave = tid >> 6, lane = tid & 63;
  int ln = lane & 15, quad = lane >> 4;
  int wm = (wave >> 1) * 64, wn = (wave & 1) * 64;
#pragma unroll
  for (int i = 0; i < 4; ++i)
#pragma unroll
    for (int j = 0; j < 4; ++j)
#pragma unroll
      for (int r = 0; r < 4; ++r) {
        int row = row0 + wm + i * 16 + quad * 4 + r;   // d index
        int col = col0 + wn + j * 16 + ln;             // token index
        Ch[swz(row, col, N_TOK)] = f2bs(acc[i][j][r]);
      }
}

// ---------- 3-term causal score GEMM (proven round-6 config) ----------
// Epilogue tweak: only the 32 diagonal blocks need the per-lane causal
// mask; the 496 off-diagonal blocks store unconditionally (uniform branch).
__global__ __launch_bounds__(256, 2) void k_score3(const short* Qh, const short* Ql,
                                                   const short* Kh, const short* Kl,
                                                   float* S) {
  // T1: 528 = 8 x 66; each XCD gets 66 consecutive triangular ids
  int bi0 = blockIdx.x;
  int bi = (bi0 & 7) * 66 + (bi0 >> 3);
  int by = (int)((sqrtf(8.f * (float)bi + 1.f) - 1.f) * 0.5f);
  while ((by + 1) * (by + 2) / 2 <= bi) ++by;
  while (by * (by + 1) / 2 > bi) --by;
  int bx = bi - by * (by + 1) / 2;
  __shared__ short lds[2 * 16384];   // 64 KB
  f32x4 acc[4][4] = {};
  gemm_core<true>(Qh, Ql, Kh, Kl, DATT >> 3, by, bx, DATT, lds, acc);
  int row0 = by * 128, col0 = bx * 128;
  int tid = threadIdx.x;
  int wave = tid >> 6, lane = tid & 63;
  int ln = lane & 15, quad = lane >> 4;
  int wm = (wave >> 1) * 64, wn = (wave & 1) * 64;
  const float scale = 0.022097086912079608f;  // 1/sqrt(2048)
  if (bx < by) {
    // strictly below the diagonal: col <= row always holds
#pragma unroll
    for (int i = 0; i < 4; ++i)
#pragma unroll
      for (int j = 0; j < 4; ++j)
#pragma unroll
        for (int r = 0; r < 4; ++r) {
          int row = row0 + wm + i * 16 + quad * 4 + r;
          int col = col0 + wn + j * 16 + ln;
          S[(size_t)row * N_TOK + col] = acc[i][j][r] * scale;
        }
  } else {
#pragma unroll
    for (int i = 0; i < 4; ++i)
#pragma unroll
      for (int j = 0; j < 4; ++j)
#pragma unroll
        for (int r = 0; r < 4; ++r) {
          int row = row0 + wm + i * 16 + quad * 4 + r;
          int col = col0 + wn + j * 16 + ln;
          if (col <= row) S[(size_t)row * N_TOK + col] = acc[i][j][r] * scale;
        }
  }
}

// ---------- softmax (round-6 proven): fp32 S -> SWIZZLED bf16 P ----------
// Zero-fill only to the 128-boundary k_out actually reads (= (band+1)*128).
__global__ __launch_bounds__(256) void k_softmax(const float* S, short* P) {
  int i = blockIdx.x;
  const float* row = S + (size_t)i * N_TOK;
  int len = i + 1;
  int tid = threadIdx.x;
  __shared__ float red[4];
  float m = -3.402823466e38f;
  for (int j = tid; j < len; j += 256) m = fmaxf(m, row[j]);
#pragma unroll
  for (int off = 32; off > 0; off >>= 1) m = fmaxf(m, __shfl_down(m, off));
  if ((tid & 63) == 0) red[tid >> 6] = m;
  __syncthreads();
  m = fmaxf(fmaxf(red[0], red[1]), fmaxf(red[2], red[3]));
  __syncthreads();
  float s = 0.f;
  for (int j = tid; j < len; j += 256) s += __expf(row[j] - m);
#pragma unroll
  for (int off = 32; off > 0; off >>= 1) s += __shfl_down(s, off);
  if ((tid & 63) == 0) red[tid >> 6] = s;
  __syncthreads();
  s = red[0] + red[1] + red[2] + red[3];
  float inv = 1.f / s;
  size_t rbase = ((size_t)(i >> 7) * (N_TOK >> 3) << 10) + (size_t)((i & 127) << 3);
  for (int j = tid; j < len; j += 256)
    P[rbase + ((size_t)(j >> 3) << 10) + (j & 7)] = f2bs(__expf(row[j] - m) * inv);
  int fillend = (len + 127) & ~127;   // only k_out's own band reads the pad
  for (int j = len + tid; j < fillend; j += 256)
    P[rbase + ((size_t)(j >> 3) << 10) + (j & 7)] = 0;
}

// ---------- 1-term depth-2 out GEMM: O = P @ Vt^T, causal k-limit ----------
// Balanced band pairing: bid and bid+256 map to bands b and 31-b.
__global__ __launch_bounds__(256, 3) void k_out(const short* Ph, const short* Vh,
                                                void* Co, const int* flagp) {
  __shared__ short lds[3 * 8192];   // 48 KB
  int bid = blockIdx.x;
  int half = bid >> 8;              // 0: heavy bands 31..16, 1: light 0..15
  int r = bid & 255;
  int s = ((r & 7) << 5) | (r >> 3);
  int bb = s >> 4;
  int band = half ? bb : (31 - bb);
  int row0 = band << 7, col0 = (s & 15) << 7;
  f32x4 acc[4][4] = {};
  gemm1d2(Ph, Vh, N_TOK >> 3, row0 >> 7, col0 >> 7, row0 + 128, lds, acc);
  int isbf = *flagp;
  int tid = threadIdx.x;
  int wave = tid >> 6, lane = tid & 63;
  int ln = lane & 15, quad = lane >> 4;
  int wm = (wave >> 1) * 64, wn = (wave & 1) * 64;
#pragma unroll
  for (int i = 0; i < 4; ++i)
#pragma unroll
    for (int j = 0; j < 4; ++j)
#pragma unroll
      for (int r2 = 0; r2 < 4; ++r2) {
        int row = row0 + wm + i * 16 + quad * 4 + r2;
        int col = col0 + wn + j * 16 + ln;
        size_t idx = (size_t)row * DATT + col;
        if (isbf) ((__hip_bfloat16*)Co)[idx] = __float2bfloat16(acc[i][j][r2]);
        else      ((float*)Co)[idx] = acc[i][j][r2];
      }
}

extern "C" void kernel_launch(void* const* d_in, const int* in_sizes, int n_in,
                              void* d_out, int out_size, void* d_ws, size_t ws_size,
                              hipStream_t stream) {
  const void* X  = d_in[0];
  const void* WQ = d_in[1];
  const void* WK = d_in[2];
  const void* WV = d_in[3];

  float* ws   = (float*)d_ws;
  int*   flag = (int*)d_ws;
  float* xbar = ws + 256;
  float* kbar = ws + 2560;
  short* p0   = (short*)(ws + 16384);
  const size_t M8 = (size_t)N_TOK * DATT;
  const size_t M4 = (size_t)EMB * DATT;
  short* Xh  = p0;
  short* Xl  = Xh + M8;
  short* Wth = Xl + M8;
  short* Wtl = Wth + M4;
  float* S   = (float*)p0;
  short* Qh  = p0 + 4 * M8;
  short* Ql  = Qh + M8;
  short* Kh  = Ql + M8;
  short* Kl  = Kh + M8;
  short* Vt  = Kl + M8;
  short* P   = Qh;   // overlay: Qh/Ql dead after score

  dim3 blk(256);
  dim3 blk512(512);

  k_sniff<<<1, 64, 0, stream>>>(X, flag);
  k_xbar<<<EMB / 256, blk, 0, stream>>>(X, xbar, flag);
  k_split_x<<<(N_TOK * EMB) / 1024, blk, 0, stream>>>(X, Xh, Xl, flag);

  dim3 gt(DATT / 64, EMB / 64);

  // Q = X @ WQ -> swizzled hi/lo
  k_transpose_split<<<gt, blk, 0, stream>>>(WQ, Wth, Wtl, EMB, DATT, flag, 1);
  k_proj3<<<dim3(256), blk512, 0, stream>>>(Xh, Xl, Wth, Wtl, Qh, Ql, nullptr);
  // K~ = X @ WK - kbar -> swizzled hi/lo
  k_transpose_split<<<gt, blk, 0, stream>>>(WK, Wth, Wtl, EMB, DATT, flag, 1);
  k_kbar<<<DATT, blk, 0, stream>>>(Wth, Wtl, xbar, kbar);
  k_proj3<<<dim3(256), blk512, 0, stream>>>(Xh, Xl, Wth, Wtl, Kh, Kl, kbar);
  // Vt = (X @ WV)^T, 1-term, swizzled (kdim = N_TOK)
  k_transpose_split<<<gt, blk, 0, stream>>>(WV, Wth, nullptr, EMB, DATT, flag, 0);
  k_proj1<<<dim3(512), blk, 0, stream>>>(Wth, Xh, Vt);

  // causal scores: 528 triangular blocks (8 XCD x 66), proven config
  k_score3<<<dim3(528), blk, 0, stream>>>(Qh, Ql, Kh, Kl, S);

  k_softmax<<<dim3(N_TOK), blk, 0, stream>>>(S, P);

  k_out<<<dim3(512), blk, 0, stream>>>(P, Vt, d_out, flag);
}

// Round 11
// 617.133 us; speedup vs baseline: 1.0499x; 1.0499x over previous
//
#include <hip/hip_runtime.h>
#include <hip/hip_bf16.h>
#include <cstdint>
#include <cstddef>
#include <cmath>

#define N_TOK 4096
#define EMB   2048
#define DATT  2048

typedef __attribute__((ext_vector_type(8))) short short8;
typedef __attribute__((ext_vector_type(4))) short shortx4;
typedef __attribute__((ext_vector_type(4))) float f32x4;

#define MFMA(a, b, c) __builtin_amdgcn_mfma_f32_16x16x32_bf16(a, b, c, 0, 0, 0)

__device__ __forceinline__ short f2bs(float f) {
  __hip_bfloat16 h = __float2bfloat16(f);   // RNE
  return __builtin_bit_cast(short, h);
}
__device__ __forceinline__ float bs2f(short s) {
  return __uint_as_float(((unsigned)(unsigned short)s) << 16);
}
__device__ __forceinline__ float ldin(const void* p, size_t i, int isbf) {
  if (isbf) {
    unsigned short u = ((const unsigned short*)p)[i];
    return __uint_as_float(((unsigned int)u) << 16);
  }
  return ((const float*)p)[i];
}

// Fragment-major swizzle: element (r, c) of an (R x K) operand lives at
//   ((r>>7)*(K/8) + (c>>3))*1024 + (r&127)*8 + (c&7)
__device__ __forceinline__ size_t swz(int r, int c, int kdim) {
  return ((size_t)((r >> 7) * (kdim >> 3) + (c >> 3)) << 10) +
         (size_t)((r & 127) << 3) + (c & 7);
}

// async global->LDS, 16B per lane; lds dest must be wave-uniform base
__device__ __forceinline__ void gl16(const short* g, short* l) {
  __builtin_amdgcn_global_load_lds(
      (const __attribute__((address_space(1))) unsigned int*)(const void*)g,
      (__attribute__((address_space(3))) unsigned int*)(void*)l, 16, 0, 0);
}

// ======================================================================
// 128x128-tile, 4-wave, 2-buffer GEMM core (proven: score3 @120us, 37% Mfma).
// stage(t+1) issued AFTER the barrier of tile t; one barrier per tile.
// ======================================================================
template <bool THREE>
__device__ __forceinline__ void gemm_core(const short* Ah, const short* Al,
                                          const short* Bh, const short* Bl,
                                          int chunks, int apan, int bpan,
                                          int kmax, short* lds,
                                          f32x4 acc[4][4]) {
  const int NSL = THREE ? 4 : 2;
  int tid = threadIdx.x;
  int lane = tid & 63;
  int wave = tid >> 6;
  int ln = lane & 15, quad = lane >> 4;
  int wm = (wave >> 1) * 64, wn = (wave & 1) * 64;
  int wofs = wave * 512;

  auto stage = [&](int b, int k0) {
    size_t ao = ((size_t)(apan * chunks + (k0 >> 3))) << 10;
    size_t bo = ((size_t)(bpan * chunks + (k0 >> 3))) << 10;
    short* base = lds + b * NSL * 4096;
    const short* sa = Ah + ao + tid * 8;
    const short* sb = Bh + bo + tid * 8;
    gl16(sa,        base + wofs);
    gl16(sa + 2048, base + wofs + 2048);
    gl16(sb,        base + 4096 + wofs);
    gl16(sb + 2048, base + 4096 + wofs + 2048);
    if (THREE) {
      const short* sal = Al + ao + tid * 8;
      const short* sbl = Bl + bo + tid * 8;
      gl16(sal,        base + 8192 + wofs);
      gl16(sal + 2048, base + 8192 + wofs + 2048);
      gl16(sbl,        base + 12288 + wofs);
      gl16(sbl + 2048, base + 12288 + wofs + 2048);
    }
  };

  stage(0, 0);
  int cur = 0;
  int abase = quad * 1024 + (wm + ln) * 8;
  int bbase = quad * 1024 + (wn + ln) * 8;
  for (int k0 = 0; k0 < kmax; k0 += 32) {
    __syncthreads();
    if (k0 + 32 < kmax) stage(cur ^ 1, k0 + 32);
    const short* B0 = lds + cur * NSL * 4096;
    short8 fah[4], fbh[4];
#pragma unroll
    for (int i = 0; i < 4; ++i) fah[i] = *(const short8*)(B0 + abase + i * 128);
#pragma unroll
    for (int j = 0; j < 4; ++j) fbh[j] = *(const short8*)(B0 + 4096 + bbase + j * 128);
    if (THREE) {
      short8 fal[4], fbl[4];
#pragma unroll
      for (int i = 0; i < 4; ++i) fal[i] = *(const short8*)(B0 + 8192 + abase + i * 128);
#pragma unroll
      for (int j = 0; j < 4; ++j) fbl[j] = *(const short8*)(B0 + 12288 + bbase + j * 128);
#pragma unroll
      for (int j = 0; j < 4; ++j)
#pragma unroll
        for (int i = 0; i < 4; ++i) {
          acc[i][j] = MFMA(fah[i], fbh[j], acc[i][j]);
          acc[i][j] = MFMA(fah[i], fbl[j], acc[i][j]);
          acc[i][j] = MFMA(fal[i], fbh[j], acc[i][j]);
        }
    } else {
#pragma unroll
      for (int j = 0; j < 4; ++j)
#pragma unroll
        for (int i = 0; i < 4; ++i) acc[i][j] = MFMA(fah[i], fbh[j], acc[i][j]);
    }
    cur ^= 1;
  }
}

// ======================================================================
// 3-term depth-2 core: (AP*128) x (BP*128) tile, AP+BP==3, 8 waves (512
// threads), 3 LDS buffers of 48KB (144KB total), ONE barrier per K-tile,
// steady-state s_waitcnt vmcnt(6); stage(t) issued during tile t-2 ->
// TWO tiles of latency cover. Used where grid == 256 (1/CU): k_proj3.
// ======================================================================
template <int AP, int BP>
__device__ __forceinline__ void gemm8(const short* __restrict__ Ah,
                                      const short* __restrict__ Al,
                                      const short* __restrict__ Bh,
                                      const short* __restrict__ Bl,
                                      int chunks, int apan, int bpan,
                                      int kmax, short* lds, f32x4 acc[4][4]) {
  constexpr int ASZ = AP * 4096;
  constexpr int BSZ = BP * 4096;
  constexpr int OAL = ASZ;
  constexpr int OBH = 2 * ASZ;
  constexpr int OBL = 2 * ASZ + BSZ;
  constexpr int BUF = 2 * ASZ + 2 * BSZ;  // 24576 shorts = 48KB
  constexpr int NNW = BP * 2;
  int tid = threadIdx.x;
  int lane = tid & 63, wave = tid >> 6;
  int ln = lane & 15, quad = lane >> 4;
  int wm = (wave / NNW) * 64, wn = (wave % NNW) * 64;
  int nt = kmax >> 5;

  auto sp = [&](int b, int t, int p) {
    short* base = lds + b * BUF;
    const short* g;
    short* l;
    if (p < AP)               { g = Ah + (((size_t)(apan + p) * chunks + (t << 2)) << 10);          l = base + p * 4096; }
    else if (p < 2 * AP)      { int q = p - AP;      g = Al + (((size_t)(apan + q) * chunks + (t << 2)) << 10); l = base + OAL + q * 4096; }
    else if (p < 2 * AP + BP) { int q = p - 2 * AP;  g = Bh + (((size_t)(bpan + q) * chunks + (t << 2)) << 10); l = base + OBH + q * 4096; }
    else                      { int q = p - 2 * AP - BP; g = Bl + (((size_t)(bpan + q) * chunks + (t << 2)) << 10); l = base + OBL + q * 4096; }
    gl16(g + tid * 8, l + wave * 512);
  };

#pragma unroll
  for (int p = 0; p < 6; ++p) sp(0, 0, p);
  if (nt > 1) {
#pragma unroll
    for (int p = 0; p < 6; ++p) sp(1, 1, p);
  }

  int abase = (wm & 128) * 32 + quad * 1024 + ((wm & 64) + ln) * 8;
  int bbase = (wn & 128) * 32 + quad * 1024 + ((wn & 64) + ln) * 8;
  int bi = 0;
  for (int t = 0; t < nt; ++t) {
    if (t + 1 < nt) asm volatile("s_waitcnt vmcnt(6)" ::: "memory");
    else            asm volatile("s_waitcnt vmcnt(0)" ::: "memory");
    __builtin_amdgcn_s_barrier();          // all waves' DMA for buf[bi] landed
    __builtin_amdgcn_sched_barrier(0);     // no LDS read hoists above

    const short* L = lds + bi * BUF;
    int pi = bi + 2; if (pi > 2) pi -= 3;
    bool pf = (t + 2 < nt);

    short8 bh[4], bl[4];
#pragma unroll
    for (int j = 0; j < 4; ++j) {
      bh[j] = *(const short8*)(L + OBH + bbase + j * 128);
      bl[j] = *(const short8*)(L + OBL + bbase + j * 128);
    }
#pragma unroll
    for (int i = 0; i < 4; ++i) {
      short8 ah = *(const short8*)(L + abase + i * 128);
      short8 al = *(const short8*)(L + OAL + abase + i * 128);
      if (pf) {                            // interleave stage issue 2/2/1/1
        if (i == 0)      { sp(pi, t + 2, 0); sp(pi, t + 2, 1); }
        else if (i == 1) { sp(pi, t + 2, 2); sp(pi, t + 2, 3); }
        else if (i == 2) { sp(pi, t + 2, 4); }
        else             { sp(pi, t + 2, 5); }
      }
      __builtin_amdgcn_s_setprio(1);
#pragma unroll
      for (int j = 0; j < 4; ++j) {
        acc[i][j] = MFMA(ah, bh[j], acc[i][j]);
        acc[i][j] = MFMA(ah, bl[j], acc[i][j]);
        acc[i][j] = MFMA(al, bh[j], acc[i][j]);
      }
      __builtin_amdgcn_s_setprio(0);
    }
    ++bi; if (bi > 2) bi = 0;
  }
}

// ======================================================================
// 1-term depth-2 core (proven): 128x128, 4 waves, 3 buffers (48KB),
// one barrier per tile, counted vmcnt(4).
// ======================================================================
__device__ __forceinline__ void gemm1d2(const short* __restrict__ Ah,
                                        const short* __restrict__ Bh,
                                        int chunks, int apan, int bpan,
                                        int kmax, short* lds, f32x4 acc[4][4]) {
  int tid = threadIdx.x;
  int lane = tid & 63, wave = tid >> 6;
  int ln = lane & 15, quad = lane >> 4;
  int wm = (wave >> 1) * 64, wn = (wave & 1) * 64;
  int wofs = wave * 512;
  int nt = kmax >> 5;

  auto stage = [&](int b, int t) {
    size_t ao = ((size_t)(apan * chunks + (t << 2))) << 10;
    size_t bo = ((size_t)(bpan * chunks + (t << 2))) << 10;
    short* base = lds + b * 8192;
    gl16(Ah + ao + tid * 8,        base + wofs);
    gl16(Ah + ao + 2048 + tid * 8, base + wofs + 2048);
    gl16(Bh + bo + tid * 8,        base + 4096 + wofs);
    gl16(Bh + bo + 2048 + tid * 8, base + 4096 + wofs + 2048);
  };
  stage(0, 0);
  if (nt > 1) stage(1, 1);

  int abase = quad * 1024 + (wm + ln) * 8;
  int bbase = quad * 1024 + (wn + ln) * 8;
  int bi = 0;
  for (int t = 0; t < nt; ++t) {
    if (t + 1 < nt) asm volatile("s_waitcnt vmcnt(4)" ::: "memory");
    else            asm volatile("s_waitcnt vmcnt(0)" ::: "memory");
    __builtin_amdgcn_s_barrier();
    __builtin_amdgcn_sched_barrier(0);
    int pi = bi + 2; if (pi > 2) pi -= 3;
    if (t + 2 < nt) stage(pi, t + 2);
    const short* L = lds + bi * 8192;
    short8 fah[4], fbh[4];
#pragma unroll
    for (int i = 0; i < 4; ++i) fah[i] = *(const short8*)(L + abase + i * 128);
#pragma unroll
    for (int j = 0; j < 4; ++j) fbh[j] = *(const short8*)(L + 4096 + bbase + j * 128);
#pragma unroll
    for (int j = 0; j < 4; ++j)
#pragma unroll
      for (int i = 0; i < 4; ++i) acc[i][j] = MFMA(fah[i], fbh[j], acc[i][j]);
    ++bi; if (bi > 2) bi = 0;
  }
}

// ---------- sniff input dtype ----------
__global__ void k_sniff(const void* x, int* flag) {
  if (threadIdx.x == 0 && blockIdx.x == 0) {
    const unsigned short* u = (const unsigned short*)x;
    int bf = 1;
    for (int i = 0; i < 256; ++i) {
      unsigned short v = u[i];
      if ((v & 0x8000u) || ((v & 0x7FFFu) >= 0x3F80u)) { bf = 0; break; }
    }
    *flag = bf;
  }
}

// ---------- xbar[e] = mean of X over first 256 rows ----------
__global__ __launch_bounds__(256) void k_xbar(const void* X, float* xbar,
                                              const int* flagp) {
  int isbf = *flagp;
  int e = blockIdx.x * 256 + threadIdx.x;
  float s = 0.f;
  for (int r = 0; r < 256; ++r) s += ldin(X, (size_t)r * EMB + e, isbf);
  xbar[e] = s * (1.f / 256.f);
}

// ---------- split X -> swizzled Xh, Xl ----------
__global__ __launch_bounds__(256) void k_split_x(const void* X, short* Xh, short* Xl,
                                                 const int* flagp) {
  int isbf = *flagp;
  size_t base = ((size_t)blockIdx.x * 256 + threadIdx.x) * 4;
  int r = (int)(base >> 11), c = (int)(base & 2047);
  shortx4 h, l;
#pragma unroll
  for (int u = 0; u < 4; ++u) {
    float x = ldin(X, base + u, isbf);
    short hh = f2bs(x);
    h[u] = hh;
    l[u] = f2bs(x - bs2f(hh));
  }
  size_t o = swz(r, c, EMB);
  *(shortx4*)(Xh + o) = h;
  *(shortx4*)(Xl + o) = l;
}

// ---------- transpose + split W -> swizzled Wth (+ Wtl) ----------
__global__ __launch_bounds__(256) void k_transpose_split(const void* W, short* Wth,
                                                         short* Wtl, int R, int C,
                                                         const int* flagp, int wlo) {
  __shared__ float T[64][65];
  int isbf = *flagp;
  int r0 = blockIdx.y * 64, c0 = blockIdx.x * 64;
  int tid = threadIdx.x;
#pragma unroll
  for (int it = 0; it < 16; ++it) {
    int idx = tid + it * 256;
    int row = idx >> 6, col = idx & 63;
    T[row][col] = ldin(W, (size_t)(r0 + row) * C + c0 + col, isbf);
  }
  __syncthreads();
#pragma unroll
  for (int it = 0; it < 16; ++it) {
    int idx = tid + it * 256;
    int row = idx >> 6, col = idx & 63;
    float x = T[col][row];
    short h = f2bs(x);
    size_t o = swz(c0 + row, r0 + col, R);
    Wth[o] = h;
    if (wlo) Wtl[o] = f2bs(x - bs2f(h));
  }
}

// ---------- kbar[d] = sum_e xbar[e] * Wk[e][d] ----------
__global__ __launch_bounds__(256) void k_kbar(const short* Wth, const short* Wtl,
                                              const float* xbar, float* kbar) {
  int d = blockIdx.x;
  float s = 0.f;
  for (int e = threadIdx.x; e < EMB; e += 256) {
    size_t o = swz(d, e, EMB);
    s += xbar[e] * (bs2f(Wth[o]) + bs2f(Wtl[o]));
  }
  __shared__ float red[4];
#pragma unroll
  for (int off = 32; off > 0; off >>= 1) s += __shfl_down(s, off);
  if ((threadIdx.x & 63) == 0) red[threadIdx.x >> 6] = s;
  __syncthreads();
  if (threadIdx.x == 0) kbar[d] = red[0] + red[1] + red[2] + red[3];
}

// ---------- 3-term depth-2 projection GEMM: 256x128 tile, 8 waves ----------
__global__ __launch_bounds__(512, 2) void k_proj3(const short* Ah, const short* Al,
                                                  const short* Bh, const short* Bl,
                                                  short* Ch, short* Cl,
                                                  const float* bias) {
  __shared__ short lds[3 * 24576];   // 144 KB, 3-buffer rotation
  int bid = blockIdx.x;
  int s = ((bid & 7) << 5) | (bid >> 3);
  int row0 = (s >> 4) << 8, col0 = (s & 15) << 7;
  f32x4 acc[4][4] = {};
  gemm8<2, 1>(Ah, Al, Bh, Bl, EMB >> 3, row0 >> 7, col0 >> 7, EMB, lds, acc);
  int tid = threadIdx.x;
  int wave = tid >> 6, lane = tid & 63;
  int ln = lane & 15, quad = lane >> 4;
  int wm = (wave >> 1) * 64, wn = (wave & 1) * 64;   // NNW=2
#pragma unroll
  for (int i = 0; i < 4; ++i)
#pragma unroll
    for (int j = 0; j < 4; ++j)
#pragma unroll
      for (int r = 0; r < 4; ++r) {
        int row = row0 + wm + i * 16 + quad * 4 + r;
        int col = col0 + wn + j * 16 + ln;
        float x = acc[i][j][r];
        if (bias) x -= bias[col];
        short h = f2bs(x);
        size_t o = swz(row, col, DATT);
        Ch[o] = h;
        Cl[o] = f2bs(x - bs2f(h));
      }
}

// ======================================================================
// FUSED: causal score (blocks 0..527, proven round-10 path, band-packed S)
//      + V projection (blocks 528..1039, proven gemm1d2 path).
// Mechanism: score3 at 2 blocks/CU needs 2.06 scheduling rounds; round 2
// runs 16 blocks on a ~97%-idle machine. proj1's 512 blocks backfill that
// idle capacity instead of running serially afterwards.
// Band-packed S: row i (band b=i>>7) has padded length 128*(b+1);
// rowoff(i) = 16384*b*(b+1)/2 + (i&127)*128*(b+1). 34.6MB total, placed
// over the dead [Xl|Wth|Wtl|pad-head] region so Xh stays live for proj.
// ======================================================================
__global__ __launch_bounds__(256, 2) void k_score_pv(
    const short* Qh, const short* Ql, const short* Kh, const short* Kl,
    float* Spk, const short* Wvt, const short* Xh, short* Vt) {
  __shared__ short lds[2 * 16384];   // 64 KB (score uses all; proj uses 48KB)
  int bid = blockIdx.x;
  int tid = threadIdx.x;
  int wave = tid >> 6, lane = tid & 63;
  int ln = lane & 15, quad = lane >> 4;
  int wm = (wave >> 1) * 64, wn = (wave & 1) * 64;

  if (bid < 528) {
    // ---- score role: T1 XCD swizzle over 528 = 8 x 66 triangular ids ----
    int bi = (bid & 7) * 66 + (bid >> 3);
    int by = (int)((sqrtf(8.f * (float)bi + 1.f) - 1.f) * 0.5f);
    while ((by + 1) * (by + 2) / 2 <= bi) ++by;
    while (by * (by + 1) / 2 > bi) --by;
    int bx = bi - by * (by + 1) / 2;
    f32x4 acc[4][4] = {};
    gemm_core<true>(Qh, Ql, Kh, Kl, DATT >> 3, by, bx, DATT, lds, acc);
    int row0 = by * 128, col0 = bx * 128;
    const float scale = 0.022097086912079608f;  // 1/sqrt(2048)
    size_t base_b = (size_t)16384 * (size_t)(by * (by + 1) / 2);
    int rstride = 128 * (by + 1);               // padded row length (floats)
    if (bx < by) {
      // strictly below the diagonal: col <= row always holds
#pragma unroll
      for (int i = 0; i < 4; ++i)
#pragma unroll
        for (int j = 0; j < 4; ++j)
#pragma unroll
          for (int r = 0; r < 4; ++r) {
            int rr = wm + i * 16 + quad * 4 + r;    // row - row0
            int col = col0 + wn + j * 16 + ln;
            Spk[base_b + (size_t)rr * rstride + col] = acc[i][j][r] * scale;
          }
    } else {
#pragma unroll
      for (int i = 0; i < 4; ++i)
#pragma unroll
        for (int j = 0; j < 4; ++j)
#pragma unroll
          for (int r = 0; r < 4; ++r) {
            int rr = wm + i * 16 + quad * 4 + r;
            int col = col0 + wn + j * 16 + ln;
            if (col <= row0 + rr)
              Spk[base_b + (size_t)rr * rstride + col] = acc[i][j][r] * scale;
          }
    }
  } else {
    // ---- V-projection role: Vt = Wvt @ Xh^T, swizzled out (kdim=N_TOK) ----
    int pid = bid - 528;
    int s = ((pid & 7) << 6) | (pid >> 3);
    int row0 = (s >> 5) << 7, col0 = (s & 31) << 7;   // row=d band, col=token
    f32x4 acc[4][4] = {};
    gemm1d2(Wvt, Xh, EMB >> 3, row0 >> 7, col0 >> 7, EMB, lds, acc);
#pragma unroll
    for (int i = 0; i < 4; ++i)
#pragma unroll
      for (int j = 0; j < 4; ++j)
#pragma unroll
        for (int r = 0; r < 4; ++r) {
          int row = row0 + wm + i * 16 + quad * 4 + r;   // d index
          int col = col0 + wn + j * 16 + ln;             // token index
          Vt[swz(row, col, N_TOK)] = f2bs(acc[i][j][r]);
        }
  }
}

// ---------- softmax (round-6 proven, band-packed S): -> SWIZZLED bf16 P ----------
__global__ __launch_bounds__(256) void k_softmax(const float* Spk, short* P) {
  int i = blockIdx.x;
  int b = i >> 7;
  const float* row = Spk + (size_t)16384 * (size_t)(b * (b + 1) / 2)
                         + (size_t)(i & 127) * (128 * (b + 1));
  int len = i + 1;
  int tid = threadIdx.x;
  __shared__ float red[4];
  float m = -3.402823466e38f;
  for (int j = tid; j < len; j += 256) m = fmaxf(m, row[j]);
#pragma unroll
  for (int off = 32; off > 0; off >>= 1) m = fmaxf(m, __shfl_down(m, off));
  if ((tid & 63) == 0) red[tid >> 6] = m;
  __syncthreads();
  m = fmaxf(fmaxf(red[0], red[1]), fmaxf(red[2], red[3]));
  __syncthreads();
  float s = 0.f;
  for (int j = tid; j < len; j += 256) s += __expf(row[j] - m);
#pragma unroll
  for (int off = 32; off > 0; off >>= 1) s += __shfl_down(s, off);
  if ((tid & 63) == 0) red[tid >> 6] = s;
  __syncthreads();
  s = red[0] + red[1] + red[2] + red[3];
  float inv = 1.f / s;
  size_t rbase = ((size_t)(i >> 7) * (N_TOK >> 3) << 10) + (size_t)((i & 127) << 3);
  for (int j = tid; j < len; j += 256)
    P[rbase + ((size_t)(j >> 3) << 10) + (j & 7)] = f2bs(__expf(row[j] - m) * inv);
  int fillend = (len + 127) & ~127;   // only k_out's own band reads the pad
  for (int j = len + tid; j < fillend; j += 256)
    P[rbase + ((size_t)(j >> 3) << 10) + (j & 7)] = 0;
}

// ---------- 1-term depth-2 out GEMM: O = P @ Vt^T, causal k-limit ----------
// Balanced band pairing: bid and bid+256 map to bands b and 31-b.
__global__ __launch_bounds__(256, 3) void k_out(const short* Ph, const short* Vh,
                                                void* Co, const int* flagp) {
  __shared__ short lds[3 * 8192];   // 48 KB
  int bid = blockIdx.x;
  int half = bid >> 8;              // 0: heavy bands 31..16, 1: light 0..15
  int r = bid & 255;
  int s = ((r & 7) << 5) | (r >> 3);
  int bb = s >> 4;
  int band = half ? bb : (31 - bb);
  int row0 = band << 7, col0 = (s & 15) << 7;
  f32x4 acc[4][4] = {};
  gemm1d2(Ph, Vh, N_TOK >> 3, row0 >> 7, col0 >> 7, row0 + 128, lds, acc);
  int isbf = *flagp;
  int tid = threadIdx.x;
  int wave = tid >> 6, lane = tid & 63;
  int ln = lane & 15, quad = lane >> 4;
  int wm = (wave >> 1) * 64, wn = (wave & 1) * 64;
#pragma unroll
  for (int i = 0; i < 4; ++i)
#pragma unroll
    for (int j = 0; j < 4; ++j)
#pragma unroll
      for (int r2 = 0; r2 < 4; ++r2) {
        int row = row0 + wm + i * 16 + quad * 4 + r2;
        int col = col0 + wn + j * 16 + ln;
        size_t idx = (size_t)row * DATT + col;
        if (isbf) ((__hip_bfloat16*)Co)[idx] = __float2bfloat16(acc[i][j][r2]);
        else      ((float*)Co)[idx] = acc[i][j][r2];
      }
}

extern "C" void kernel_launch(void* const* d_in, const int* in_sizes, int n_in,
                              void* d_out, int out_size, void* d_ws, size_t ws_size,
                              hipStream_t stream) {
  const void* X  = d_in[0];
  const void* WQ = d_in[1];
  const void* WK = d_in[2];
  const void* WV = d_in[3];

  // Map (shorts from p0 = d_ws + 64KB), byte offsets from p0:
  //  [Xh 16M)[Xl 16M)[Wth 8M)[Wtl 8M)[pad 16M) | [Qh)[Ql)[Kh)[Kl) 16M each | [Vt 16M)
  //  Spk (band-packed fp32 S, 34.6MB) overlays [16M..50.6M) = Xl|Wth|Wtl|pad-head
  //  (all dead during the fused kernel; Xh stays LIVE for the V-projection).
  //  Wvt (8MB) lives at [56M..64M) = pad tail. P overlays Qh (dead after score).
  float* ws   = (float*)d_ws;
  int*   flag = (int*)d_ws;
  float* xbar = ws + 256;
  float* kbar = ws + 2560;
  short* p0   = (short*)(ws + 16384);
  const size_t M8 = (size_t)N_TOK * DATT;   // 8M shorts = 16MB
  const size_t M4 = (size_t)EMB * DATT;     // 4M shorts = 8MB
  short* Xh  = p0;
  short* Xl  = Xh + M8;
  short* Wth = Xl + M8;
  short* Wtl = Wth + M4;
  float* Spk = (float*)(p0 + M8);           // byte 16M.. (needs 34.6MB, < 56M) 
  short* Wvt = p0 + 4 * M8 - M4;            // byte 56M..64M (pad tail)
  short* Qh  = p0 + 4 * M8;
  short* Ql  = Qh + M8;
  short* Kh  = Ql + M8;
  short* Kl  = Kh + M8;
  short* Vt  = Kl + M8;
  short* P   = Qh;   // overlay: Qh/Ql dead after score

  dim3 blk(256);
  dim3 blk512(512);

  k_sniff<<<1, 64, 0, stream>>>(X, flag);
  k_xbar<<<EMB / 256, blk, 0, stream>>>(X, xbar, flag);
  k_split_x<<<(N_TOK * EMB) / 1024, blk, 0, stream>>>(X, Xh, Xl, flag);

  dim3 gt(DATT / 64, EMB / 64);

  // Q = X @ WQ -> swizzled hi/lo
  k_transpose_split<<<gt, blk, 0, stream>>>(WQ, Wth, Wtl, EMB, DATT, flag, 1);
  k_proj3<<<dim3(256), blk512, 0, stream>>>(Xh, Xl, Wth, Wtl, Qh, Ql, nullptr);
  // K~ = X @ WK - kbar -> swizzled hi/lo
  k_transpose_split<<<gt, blk, 0, stream>>>(WK, Wth, Wtl, EMB, DATT, flag, 1);
  k_kbar<<<DATT, blk, 0, stream>>>(Wth, Wtl, xbar, kbar);
  k_proj3<<<dim3(256), blk512, 0, stream>>>(Xh, Xl, Wth, Wtl, Kh, Kl, kbar);
  // WV^T -> its own Wvt slot (pad tail) so the fused kernel can read it
  k_transpose_split<<<gt, blk, 0, stream>>>(WV, Wvt, nullptr, EMB, DATT, flag, 0);

  // FUSED: 528 causal-score blocks + 512 V-projection blocks in one launch.
  // proj blocks backfill the score grid's 2nd-round idle capacity.
  k_score_pv<<<dim3(1040), blk, 0, stream>>>(Qh, Ql, Kh, Kl, Spk, Wvt, Xh, Vt);

  k_softmax<<<dim3(N_TOK), blk, 0, stream>>>(Spk, P);

  k_out<<<dim3(512), blk, 0, stream>>>(P, Vt, d_out, flag);
}